// Round 1
// baseline (529.190 us; speedup 1.0000x reference)
//
#include <hip/hip_runtime.h>

#define SEQ 81
#define DIM 64
#define LDQ 68      // f32 row stride for Q/K tiles (64+4 pad -> 2-way-free banks)
#define LDS_SC 84   // score row stride (81 -> 84)
#define NTHREADS 512

static constexpr float kScale = 0.03608439182435161f;  // 1/sqrt(768)

__device__ __forceinline__ float dot4(float4 a, float4 b) {
    return a.x*b.x + a.y*b.y + a.z*b.z + a.w*b.w;
}

// QK^T register-tiled GEMM: 3 i-rows x 6 j-cols per thread, K-dim 64 in float4 chunks.
// CAUSAL skips register tiles where every lane's (i,j) is masked:
// min over lanes of (j - i) = 16*tt - 31 - 32*ss > 0.
template<bool CAUSAL>
__device__ __forceinline__ void qk_gemm(const float* __restrict__ sQ,
                                        const float* __restrict__ sK,
                                        const int* irc, const int* jrc,
                                        float acc[3][6]) {
    for (int kc = 0; kc < 16; ++kc) {
        float4 q[3];
        #pragma unroll
        for (int ss = 0; ss < 3; ++ss)
            q[ss] = *reinterpret_cast<const float4*>(sQ + irc[ss]*LDQ + kc*4);
        #pragma unroll
        for (int tt = 0; tt < 6; ++tt) {
            float4 k = *reinterpret_cast<const float4*>(sK + jrc[tt]*LDQ + kc*4);
            #pragma unroll
            for (int ss = 0; ss < 3; ++ss) {
                if (CAUSAL && (16*tt > 31 + 32*ss)) continue;  // fully-masked tile
                acc[ss][tt] += dot4(q[ss], k);
            }
        }
    }
}

// Qe GEMM: Qe[i][rp] = Q[i] . emb_table[rbase+rp], rp in [0,80].
// emb rows read from global (20.7 KB slice, L1-resident across the 16 k-chunks).
__device__ __forceinline__ void qe_gemm(const float* __restrict__ sQ,
                                        const float* __restrict__ emb,
                                        const int* irc, const int* jrc,
                                        int rbase, float acc[3][6]) {
    for (int kc = 0; kc < 16; ++kc) {
        float4 q[3];
        #pragma unroll
        for (int ss = 0; ss < 3; ++ss)
            q[ss] = *reinterpret_cast<const float4*>(sQ + irc[ss]*LDQ + kc*4);
        #pragma unroll
        for (int tt = 0; tt < 6; ++tt) {
            float4 e = *reinterpret_cast<const float4*>(emb + (size_t)(rbase + jrc[tt])*DIM + kc*4);
            #pragma unroll
            for (int ss = 0; ss < 3; ++ss)
                acc[ss][tt] += dot4(q[ss], e);
        }
    }
}

__global__ __launch_bounds__(NTHREADS)
void rpsa_kernel(const float* __restrict__ Q, const float* __restrict__ K,
                 const float* __restrict__ V, const float* __restrict__ emb,
                 const int* __restrict__ ucp, float* __restrict__ out)
{
    extern __shared__ float sm[];
    float* sQ = sm;                      // 81*68 = 5508
    float* sK = sQ + SEQ*LDQ;            // 5508
    float* sV = sK + SEQ*LDQ;            // 81*64 = 5184
    float* sS = sV + SEQ*DIM;            // 81*84 = 6804   (total 92016 B)

    const int tid = threadIdx.x;
    const int bh  = blockIdx.x;
    const size_t base = (size_t)bh * (SEQ*DIM);
    const int uc = ucp[0];

    // ---- Phase 0: stage Q,K,V into LDS (coalesced float4) ----
    for (int u = tid; u < SEQ*DIM/4; u += NTHREADS) {
        const int row = u >> 4, c4 = (u & 15) * 4;
        *reinterpret_cast<float4*>(sQ + row*LDQ + c4) = *reinterpret_cast<const float4*>(Q + base + u*4);
        *reinterpret_cast<float4*>(sK + row*LDQ + c4) = *reinterpret_cast<const float4*>(K + base + u*4);
        *reinterpret_cast<float4*>(sV + row*DIM + c4) = *reinterpret_cast<const float4*>(V + base + u*4);
    }
    __syncthreads();

    const int tj = tid & 15;       // 0..15
    const int ti = tid >> 4;       // 0..31
    int ir[3], jr[6], irc[3], jrc[6];
    bool iv[3], jv[6];
    #pragma unroll
    for (int ss = 0; ss < 3; ++ss) {
        ir[ss] = ti + 32*ss; iv[ss] = ir[ss] < SEQ; irc[ss] = iv[ss] ? ir[ss] : SEQ-1;
    }
    #pragma unroll
    for (int tt = 0; tt < 6; ++tt) {
        jr[tt] = tj + 16*tt; jv[tt] = jr[tt] < SEQ; jrc[tt] = jv[tt] ? jr[tt] : SEQ-1;
    }

    // ---- Phase 1: scores = QK^T * scale (+ causal mask) ----
    {
        float acc[3][6] = {};
        if (uc) qk_gemm<true >(sQ, sK, irc, jrc, acc);
        else    qk_gemm<false>(sQ, sK, irc, jrc, acc);
        #pragma unroll
        for (int ss = 0; ss < 3; ++ss) {
            #pragma unroll
            for (int tt = 0; tt < 6; ++tt) {
                if (!iv[ss] || !jv[tt]) continue;
                float s = acc[ss][tt] * kScale;
                if (uc && jr[tt] > ir[ss]) s -= 1e9f;
                sS[ir[ss]*LDS_SC + jr[tt]] = s;
            }
        }
    }
    __syncthreads();

    // ---- Phase 2: relative-position bias via two Qe passes ----
    // rel = 80 + i - j.  j > i  => rel in [0,79]   (pass 0, skipped when causal)
    //                    j <= i => rel in [80,160] (pass 1)
    // Scatter-add Qe[i][rp] directly into sS[i][j]; triangles are disjoint -> race-free.
    for (int pass = 0; pass < 2; ++pass) {
        if (pass == 0 && uc) continue;
        const int rbase = (pass == 0) ? 0 : (SEQ - 1);
        float acc[3][6] = {};
        qe_gemm(sQ, emb, irc, jrc, rbase, acc);
        #pragma unroll
        for (int ss = 0; ss < 3; ++ss) {
            #pragma unroll
            for (int tt = 0; tt < 6; ++tt) {
                if (!iv[ss] || !jv[tt]) continue;
                const int i = ir[ss], rp = jr[tt];
                const int j = (pass == 0) ? (SEQ - 1 + i - rp) : (i - rp);
                const bool ok = (pass == 0) ? (j > i && j < SEQ) : (j >= 0);
                if (ok) sS[i*LDS_SC + j] += acc[ss][tt] * kScale;
            }
        }
    }
    __syncthreads();

    // ---- Phase 3: row softmax (serial per row; 81 of 512 threads) ----
    if (tid < SEQ) {
        float* row = sS + tid*LDS_SC;
        float m = -1e30f;
        for (int j = 0; j < SEQ; ++j) m = fmaxf(m, row[j]);
        float s = 0.f;
        for (int j = 0; j < SEQ; ++j) { float e = __expf(row[j] - m); row[j] = e; s += e; }
        const float inv = 1.f / s;
        for (int j = 0; j < SEQ; ++j) row[j] *= inv;
    }
    __syncthreads();

    // ---- Phase 4: out = P @ V ; thread owns 3 i-rows x float4 d-chunk ----
    float4 o[3];
    #pragma unroll
    for (int ss = 0; ss < 3; ++ss) o[ss] = make_float4(0.f, 0.f, 0.f, 0.f);
    for (int j = 0; j < SEQ; ++j) {
        float4 v = *reinterpret_cast<const float4*>(sV + j*DIM + tj*4);
        #pragma unroll
        for (int ss = 0; ss < 3; ++ss) {
            const float p = sS[irc[ss]*LDS_SC + j];
            o[ss].x += p*v.x; o[ss].y += p*v.y; o[ss].z += p*v.z; o[ss].w += p*v.w;
        }
    }
    #pragma unroll
    for (int ss = 0; ss < 3; ++ss)
        if (iv[ss])
            *reinterpret_cast<float4*>(out + base + ir[ss]*DIM + tj*4) = o[ss];
}

extern "C" void kernel_launch(void* const* d_in, const int* in_sizes, int n_in,
                              void* d_out, int out_size, void* d_ws, size_t ws_size,
                              hipStream_t stream) {
    const float* Q   = (const float*)d_in[0];
    const float* K   = (const float*)d_in[1];
    const float* V   = (const float*)d_in[2];
    const float* emb = (const float*)d_in[3];
    const int*   uc  = (const int*)d_in[4];
    float* out = (float*)d_out;

    const int nbh = in_sizes[0] / (SEQ * DIM);  // 4096
    const size_t smem = (size_t)(SEQ*LDQ*2 + SEQ*DIM + SEQ*LDS_SC) * sizeof(float);  // 92016 B
    hipFuncSetAttribute(reinterpret_cast<const void*>(rpsa_kernel),
                        hipFuncAttributeMaxDynamicSharedMemorySize, (int)smem);
    rpsa_kernel<<<nbh, NTHREADS, smem, stream>>>(Q, K, V, emb, uc, out);
}

// Round 2
// 112.966 us; speedup vs baseline: 4.6845x; 4.6845x over previous
//
#include <hip/hip_runtime.h>

#define SEQ 81
#define SP 96            // padded row count (6 x 16)
#define DIM 64
#define NT 384           // 6 waves
#define NW 6
#define LDS_S 100        // f32 stride for score matrix

typedef short bf16x8  __attribute__((ext_vector_type(8)));
typedef short short4v __attribute__((ext_vector_type(4)));
typedef float f32x4   __attribute__((ext_vector_type(4)));

static constexpr float kScale = 0.03608439182435161f;  // 1/sqrt(768)

__device__ __forceinline__ short f2bf(float f) {
    unsigned u = __builtin_bit_cast(unsigned, f);
    u = (u + 0x7FFFu + ((u >> 16) & 1u)) >> 16;   // RNE; inputs finite
    return (short)u;
}

__global__ void emb_cvt_kernel(const float* __restrict__ in, short* __restrict__ out, int n) {
    int i = blockIdx.x * 256 + threadIdx.x;
    if (i < n) out[i] = f2bf(in[i]);
}

__global__ __launch_bounds__(NT)
void rpsa_kernel(const float* __restrict__ Q, const float* __restrict__ K,
                 const float* __restrict__ V, const short* __restrict__ embw,
                 const int* __restrict__ ucp, float* __restrict__ out)
{
    extern __shared__ char smraw[];
    short* sQ  = (short*)smraw;              // [96][64]  bf16, XOR-swizzled rows
    short* sK  = sQ + SP * DIM;              // [96][64]
    short* sVt = sK + SP * DIM;              // [64][128] bf16, sVt[d][j], swizzled
    float* sS  = (float*)(sVt + DIM * 128);  // [96][100] f32 scores
    short* sP  = sQ;                         // [96][128] bf16 P, overlays sQ/sK after use

    const int tid = threadIdx.x;
    const int bh  = blockIdx.x;
    const size_t base = (size_t)bh * (SEQ * DIM);
    const int uc = ucp[0];

    // ---- stage Q, K as bf16 (rows >= 81 zeroed) ----
    for (int u = tid; u < SP * DIM / 8; u += NT) {
        const int row = u >> 3;
        const int so  = (u & 7) * 8;
        bf16x8 qb = {0,0,0,0,0,0,0,0}, kb = {0,0,0,0,0,0,0,0};
        if (row < SEQ) {
            const float* qp = Q + base + row * DIM + so;
            const float* kp = K + base + row * DIM + so;
            #pragma unroll
            for (int t = 0; t < 8; ++t) { qb[t] = f2bf(qp[t]); kb[t] = f2bf(kp[t]); }
        }
        const int idx = row * DIM + (so ^ (8 * (row & 7)));
        *(bf16x8*)(sQ + idx) = qb;
        *(bf16x8*)(sK + idx) = kb;
    }
    // ---- stage V transposed: sVt[d][j] ----
    for (int u = tid; u < SEQ * DIM / 4; u += NT) {
        const int j = u >> 4, d4 = (u & 15) * 4;
        float4 v = *(const float4*)(V + base + j * DIM + d4);
        sVt[(d4+0)*128 + (j ^ (8*((d4+0)&7)))] = f2bf(v.x);
        sVt[(d4+1)*128 + (j ^ (8*((d4+1)&7)))] = f2bf(v.y);
        sVt[(d4+2)*128 + (j ^ (8*((d4+2)&7)))] = f2bf(v.z);
        sVt[(d4+3)*128 + (j ^ (8*((d4+3)&7)))] = f2bf(v.w);
    }
    for (int u = tid; u < DIM * 16; u += NT) {          // zero pad cols j in [81,96]
        const int d = u >> 4, j = SEQ + (u & 15);
        sVt[d*128 + (j ^ (8*(d&7)))] = 0;
    }
    __syncthreads();

    const int w = tid >> 6, L = tid & 63;
    const int lr = L & 15, lg = L >> 4;

    // A-fragments: Q rows of this wave's band. A[row=lane&15][k=8*(lane>>4)+t]
    bf16x8 aq[2];
    {
        const int row = 16*w + lr;
        #pragma unroll
        for (int ks = 0; ks < 2; ++ks)
            aq[ks] = *(const bf16x8*)(sQ + row*DIM + ((32*ks + 8*lg) ^ (8*(row&7))));
    }

    // ---- QK^T: C[i=16w+4*lg+r][j=16nt+lr]; causal skips tiles nt > w ----
    const int ntEnd = uc ? w : (NW - 1);
    for (int nt = 0; nt <= ntEnd; ++nt) {
        f32x4 acc = {0.f,0.f,0.f,0.f};
        #pragma unroll
        for (int ks = 0; ks < 2; ++ks) {
            const int row = 16*nt + lr;
            bf16x8 b = *(const bf16x8*)(sK + row*DIM + ((32*ks + 8*lg) ^ (8*(row&7))));
            acc = __builtin_amdgcn_mfma_f32_16x16x32_bf16(aq[ks], b, acc, 0, 0, 0);
        }
        #pragma unroll
        for (int r = 0; r < 4; ++r)
            sS[(16*w + 4*lg + r)*LDS_S + 16*nt + lr] = acc[r] * kScale;
    }

    // ---- Qe pass 1: rel = 80 + (i-j), j <= i  (always needed) ----
    // Qe[i][rp] = Q[i] . emb[80+rp]; scatter j = i - rp. Rows hit = own band -> race-free.
    for (int nt = 0; nt <= w; ++nt) {
        f32x4 acc = {0.f,0.f,0.f,0.f};
        int erow = (SEQ - 1) + 16*nt + lr;
        if (erow > 2*SEQ) erow = 2*SEQ;      // clamp pad lanes into table (harmless)
        #pragma unroll
        for (int ks = 0; ks < 2; ++ks) {
            bf16x8 b = *(const bf16x8*)(embw + erow*DIM + 32*ks + 8*lg);
            acc = __builtin_amdgcn_mfma_f32_16x16x32_bf16(aq[ks], b, acc, 0, 0, 0);
        }
        #pragma unroll
        for (int r = 0; r < 4; ++r) {
            const int i = 16*w + 4*lg + r;
            const int j = i - (16*nt + lr);
            if (j >= 0) sS[i*LDS_S + j] += acc[r] * kScale;
        }
    }
    // ---- Qe pass 0: rel = rp in [0,79], j = 80+i-rp > i (non-causal only) ----
    if (!uc) {
        for (int nt = w; nt < NW; ++nt) {
            f32x4 acc = {0.f,0.f,0.f,0.f};
            const int erow = 16*nt + lr;     // <= 95 < 163, in-bounds
            #pragma unroll
            for (int ks = 0; ks < 2; ++ks) {
                bf16x8 b = *(const bf16x8*)(embw + erow*DIM + 32*ks + 8*lg);
                acc = __builtin_amdgcn_mfma_f32_16x16x32_bf16(aq[ks], b, acc, 0, 0, 0);
            }
            #pragma unroll
            for (int r = 0; r < 4; ++r) {
                const int i  = 16*w + 4*lg + r;
                const int rp = 16*nt + lr;
                if (rp >= i && rp < SEQ - 1)
                    sS[i*LDS_S + (SEQ - 1 + i - rp)] += acc[r] * kScale;
            }
        }
    }
    __syncthreads();   // all waves done with sQ/sK (sP overlays them) and sS complete

    // ---- softmax: 4 threads per row (rows of own wave's band), mask by exclusion ----
    {
        const int row = tid >> 2, sub = tid & 3;
        const float* rs = sS + row * LDS_S;
        int jlim = SEQ - 1;
        if (uc && row < jlim) jlim = row;    // causal: valid j <= i
        float xv[24];
        float m = -1e30f;
        #pragma unroll
        for (int k = 0; k < 6; ++k) {
            const int c = sub + 4*k;
            float4 x = *(const float4*)(rs + 4*c);
            xv[4*k+0] = x.x; xv[4*k+1] = x.y; xv[4*k+2] = x.z; xv[4*k+3] = x.w;
            #pragma unroll
            for (int e = 0; e < 4; ++e) {
                const int j = 4*c + e;
                m = fmaxf(m, (j <= jlim) ? xv[4*k+e] : -1e30f);
            }
        }
        m = fmaxf(m, __shfl_xor(m, 1, 4));
        m = fmaxf(m, __shfl_xor(m, 2, 4));
        float s = 0.f;
        #pragma unroll
        for (int k = 0; k < 6; ++k) {
            #pragma unroll
            for (int e = 0; e < 4; ++e) {
                const int j = 4*(sub + 4*k) + e;
                const float v = (j <= jlim) ? __expf(xv[4*k+e] - m) : 0.f;
                xv[4*k+e] = v; s += v;
            }
        }
        s += __shfl_xor(s, 1, 4);
        s += __shfl_xor(s, 2, 4);
        const float inv = 1.f / s;
        #pragma unroll
        for (int k = 0; k < 6; ++k) {
            const int c = sub + 4*k;
            short4v p = { f2bf(xv[4*k+0]*inv), f2bf(xv[4*k+1]*inv),
                          f2bf(xv[4*k+2]*inv), f2bf(xv[4*k+3]*inv) };
            *(short4v*)(sP + row*128 + ((4*c) ^ (8*(row&7)))) = p;
        }
    }
    // No barrier: wave w's softmax threads (rows 16w..16w+15) wrote exactly the sP
    // rows this wave's PV A-fragments read; same-wave LDS ops complete in order.

    // ---- PV: O[i][d] = sum_j P[i][j] V[j][d]; A=P (K=96), B=sVt ----
    bf16x8 ap[3];
    {
        const int row = 16*w + lr;
        #pragma unroll
        for (int ks = 0; ks < 3; ++ks)
            ap[ks] = *(const bf16x8*)(sP + row*128 + ((32*ks + 8*lg) ^ (8*(row&7))));
    }
    #pragma unroll
    for (int nt = 0; nt < 4; ++nt) {
        f32x4 acc = {0.f,0.f,0.f,0.f};
        #pragma unroll
        for (int ks = 0; ks < 3; ++ks) {
            const int d = 16*nt + lr;
            bf16x8 b = *(const bf16x8*)(sVt + d*128 + ((32*ks + 8*lg) ^ (8*(d&7))));
            acc = __builtin_amdgcn_mfma_f32_16x16x32_bf16(ap[ks], b, acc, 0, 0, 0);
        }
        #pragma unroll
        for (int r = 0; r < 4; ++r) {
            const int i = 16*w + 4*lg + r;
            if (i < SEQ) out[base + i*DIM + 16*nt + lr] = acc[r];
        }
    }
}

extern "C" void kernel_launch(void* const* d_in, const int* in_sizes, int n_in,
                              void* d_out, int out_size, void* d_ws, size_t ws_size,
                              hipStream_t stream) {
    const float* Q   = (const float*)d_in[0];
    const float* K   = (const float*)d_in[1];
    const float* V   = (const float*)d_in[2];
    const float* emb = (const float*)d_in[3];
    const int*   uc  = (const int*)d_in[4];
    float* out = (float*)d_out;

    const int nbh   = in_sizes[0] / (SEQ * DIM);   // 4096
    const int n_emb = in_sizes[3];                 // 163*64

    short* embw = (short*)d_ws;
    emb_cvt_kernel<<<(n_emb + 255) / 256, 256, 0, stream>>>(emb, embw, n_emb);

    const size_t smem = (size_t)(SP*DIM*2*2 + DIM*128*2 + SP*LDS_S*4);  // 79360 B -> 2 blocks/CU
    hipFuncSetAttribute(reinterpret_cast<const void*>(rpsa_kernel),
                        hipFuncAttributeMaxDynamicSharedMemorySize, (int)smem);
    rpsa_kernel<<<nbh, NT, smem, stream>>>(Q, K, V, embw, uc, out);
}

// Round 3
// 92.942 us; speedup vs baseline: 5.6938x; 1.2155x over previous
//
#include <hip/hip_runtime.h>

#define SEQ 81
#define SP 96            // padded rows (6 x 16)
#define DIM 64
#define NT 384           // 6 waves
#define NW 6

typedef short bf16x8  __attribute__((ext_vector_type(8)));
typedef short short4v __attribute__((ext_vector_type(4)));
typedef float f32x4   __attribute__((ext_vector_type(4)));

static constexpr float kScale = 0.03608439182435161f;  // 1/sqrt(768)

__device__ __forceinline__ short f2bf(float f) {
    unsigned u = __builtin_bit_cast(unsigned, f);
    u = (u + 0x7FFFu + ((u >> 16) & 1u)) >> 16;   // RNE; inputs finite
    return (short)u;
}
__device__ __forceinline__ float bf2f(short h) {
    unsigned u = ((unsigned)(unsigned short)h) << 16;
    return __builtin_bit_cast(float, u);
}

__global__ void emb_cvt_kernel(const float* __restrict__ in, short* __restrict__ out, int n) {
    int i = blockIdx.x * 256 + threadIdx.x;
    if (i < n) out[i] = f2bf(in[i]);
}

__global__ __launch_bounds__(NT, 6)
void rpsa_kernel(const float* __restrict__ Q, const float* __restrict__ K,
                 const float* __restrict__ V, const short* __restrict__ embw,
                 const int* __restrict__ ucp, float* __restrict__ out)
{
    extern __shared__ char smraw[];
    short* sQ  = (short*)smraw;            // [96][64]  bf16 swizzled   12288 B
    short* sK  = sQ + SP*DIM;              // [96][64]                  12288 B
    short* sVt = sK + SP*DIM;              // [64][128] sVt[d][j] swz   16384 B
    short* sP  = sQ;                       // [96][128] bias/P overlay (24576 B)
    // total 40960 B -> 4 blocks/CU

    const int tid = threadIdx.x;
    const size_t base = (size_t)blockIdx.x * (SEQ * DIM);
    const int uc = ucp[0];

    // ---- stage Q, K as bf16 (rows >= 81 zeroed) ----
    for (int u = tid; u < SP * DIM / 8; u += NT) {
        const int row = u >> 3;
        const int so  = (u & 7) * 8;
        bf16x8 qb = {0,0,0,0,0,0,0,0}, kb = {0,0,0,0,0,0,0,0};
        if (row < SEQ) {
            const f32x4 q0 = *(const f32x4*)(Q + base + row*DIM + so);
            const f32x4 q1 = *(const f32x4*)(Q + base + row*DIM + so + 4);
            const f32x4 k0 = *(const f32x4*)(K + base + row*DIM + so);
            const f32x4 k1 = *(const f32x4*)(K + base + row*DIM + so + 4);
            #pragma unroll
            for (int t = 0; t < 4; ++t) {
                qb[t] = f2bf(q0[t]); qb[4+t] = f2bf(q1[t]);
                kb[t] = f2bf(k0[t]); kb[4+t] = f2bf(k1[t]);
            }
        }
        const int idx = row*DIM + (so ^ (8*(row&7)));
        *(bf16x8*)(sQ + idx) = qb;
        *(bf16x8*)(sK + idx) = kb;
    }
    // ---- stage V transposed via 4x4 register transpose; one item per thread ----
    {
        const int j4 = tid >> 4;          // 0..23  (j block; rows >= 81 zeroed)
        const int d4 = tid & 15;          // 0..15  (d block)
        f32x4 rw[4];
        #pragma unroll
        for (int e = 0; e < 4; ++e) {
            const int j = 4*j4 + e;
            rw[e] = (j < SEQ) ? *(const f32x4*)(V + base + j*DIM + 4*d4)
                              : (f32x4){0.f,0.f,0.f,0.f};
        }
        #pragma unroll
        for (int c = 0; c < 4; ++c) {
            const int d = 4*d4 + c;
            short4v pv = { f2bf(rw[0][c]), f2bf(rw[1][c]), f2bf(rw[2][c]), f2bf(rw[3][c]) };
            *(short4v*)(sVt + d*128 + ((4*j4) ^ (8*(d&7)))) = pv;
        }
    }
    __syncthreads();   // bar1

    const int w  = tid >> 6, L = tid & 63;
    const int lr = L & 15,  lg = L >> 4;
    const int i0 = 16*w + 4*lg;           // this lane's 4 output rows: i0..i0+3

    // A-fragments (Q rows of this wave's band), held in registers for QK and Qe
    bf16x8 aq0, aq1;
    {
        const int row = 16*w + lr;
        aq0 = *(const bf16x8*)(sQ + row*DIM + ((8*lg)      ^ (8*(row&7))));
        aq1 = *(const bf16x8*)(sQ + row*DIM + ((32 + 8*lg) ^ (8*(row&7))));
    }

    // ---- QK^T into register accumulators; causal skips tiles nt > w (uniform) ----
    f32x4 accs[NW] = {};
    const int ntEnd = uc ? w : (NW - 1);
    #pragma unroll
    for (int nt = 0; nt < NW; ++nt) {
        if (nt > ntEnd) continue;
        const int row = 16*nt + lr;
        bf16x8 b0 = *(const bf16x8*)(sK + row*DIM + ((8*lg)      ^ (8*(row&7))));
        bf16x8 b1 = *(const bf16x8*)(sK + row*DIM + ((32 + 8*lg) ^ (8*(row&7))));
        f32x4 a = accs[nt];
        a = __builtin_amdgcn_mfma_f32_16x16x32_bf16(aq0, b0, a, 0, 0, 0);
        a = __builtin_amdgcn_mfma_f32_16x16x32_bf16(aq1, b1, a, 0, 0, 0);
        accs[nt] = a;
    }
    __syncthreads();   // bar2: all waves done reading sQ/sK -> overlay is safe

    // ---- Qe bias scatter into sP (bf16, same (i,j)->addr map as P) ----
    // pass 1: rel = 80 + (i-j), j <= i  (always)
    #pragma unroll
    for (int nt = 0; nt < NW; ++nt) {
        if (nt > w) continue;
        int erow = (SEQ - 1) + 16*nt + lr;
        if (erow > 2*SEQ) erow = 2*SEQ;           // clamp pad lanes (writes land in pad rows only)
        bf16x8 b0 = *(const bf16x8*)(embw + erow*DIM + 8*lg);
        bf16x8 b1 = *(const bf16x8*)(embw + erow*DIM + 32 + 8*lg);
        f32x4 a = {0.f,0.f,0.f,0.f};
        a = __builtin_amdgcn_mfma_f32_16x16x32_bf16(aq0, b0, a, 0, 0, 0);
        a = __builtin_amdgcn_mfma_f32_16x16x32_bf16(aq1, b1, a, 0, 0, 0);
        #pragma unroll
        for (int r = 0; r < 4; ++r) {
            const int i = i0 + r;
            const int j = i - (16*nt + lr);
            if (j >= 0) sP[i*128 + (j ^ (8*(i&7)))] = f2bf(a[r] * kScale);
        }
    }
    // pass 0: rel = rp in [0,79], j = 80+i-rp > i  (non-causal only)
    if (!uc) {
        #pragma unroll
        for (int nt = 0; nt < NW; ++nt) {
            if (nt < w) continue;
            const int erow = 16*nt + lr;          // <= 95 < 163
            bf16x8 b0 = *(const bf16x8*)(embw + erow*DIM + 8*lg);
            bf16x8 b1 = *(const bf16x8*)(embw + erow*DIM + 32 + 8*lg);
            f32x4 a = {0.f,0.f,0.f,0.f};
            a = __builtin_amdgcn_mfma_f32_16x16x32_bf16(aq0, b0, a, 0, 0, 0);
            a = __builtin_amdgcn_mfma_f32_16x16x32_bf16(aq1, b1, a, 0, 0, 0);
            #pragma unroll
            for (int r = 0; r < 4; ++r) {
                const int i  = i0 + r;
                const int rp = 16*nt + lr;
                if (rp >= i && rp < SEQ - 1)
                    sP[i*128 + ((SEQ - 1 + i - rp) ^ (8*(i&7)))] = f2bf(a[r] * kScale);
            }
        }
    }
    // No barrier: this wave's bias rows were written only by this wave, and are
    // read only by this wave (each (i,j) slot has a unique owner lane).

    // ---- in-register softmax: x[nt][r] = scaled QK + bias; reduce over j ----
    float x[NW][4];
    float mr[4] = {-1e30f, -1e30f, -1e30f, -1e30f};
    #pragma unroll
    for (int nt = 0; nt < NW; ++nt) {
        const bool live = (!uc) || (nt <= w);     // uniform
        const int j = 16*nt + lr;
        #pragma unroll
        for (int r = 0; r < 4; ++r) {
            const int i = i0 + r;
            float v = accs[nt][r] * kScale;
            if (live) v += bf2f(sP[i*128 + (j ^ (8*(i&7)))]);
            x[nt][r] = v;
            const int jl = uc ? (i < SEQ-1 ? i : SEQ-1) : (SEQ-1);
            if (j <= jl) mr[r] = fmaxf(mr[r], v);
        }
    }
    #pragma unroll
    for (int r = 0; r < 4; ++r) {
        float m = mr[r];
        m = fmaxf(m, __shfl_xor(m, 1, 16));
        m = fmaxf(m, __shfl_xor(m, 2, 16));
        m = fmaxf(m, __shfl_xor(m, 4, 16));
        m = fmaxf(m, __shfl_xor(m, 8, 16));
        mr[r] = m;
    }
    float sr[4] = {0.f, 0.f, 0.f, 0.f};
    #pragma unroll
    for (int nt = 0; nt < NW; ++nt) {
        const int j = 16*nt + lr;
        #pragma unroll
        for (int r = 0; r < 4; ++r) {
            const int i = i0 + r;
            const int jl = uc ? (i < SEQ-1 ? i : SEQ-1) : (SEQ-1);
            const float e = (j <= jl) ? __expf(x[nt][r] - mr[r]) : 0.f;
            x[nt][r] = e; sr[r] += e;
        }
    }
    #pragma unroll
    for (int r = 0; r < 4; ++r) {
        float s = sr[r];
        s += __shfl_xor(s, 1, 16);
        s += __shfl_xor(s, 2, 16);
        s += __shfl_xor(s, 4, 16);
        s += __shfl_xor(s, 8, 16);
        sr[r] = 1.f / s;
    }
    // ---- write P (bf16) into overlay; every (i,j<=95) slot gets written ----
    #pragma unroll
    for (int nt = 0; nt < NW; ++nt) {
        const int j = 16*nt + lr;
        #pragma unroll
        for (int r = 0; r < 4; ++r) {
            const int i = i0 + r;
            sP[i*128 + (j ^ (8*(i&7)))] = f2bf(x[nt][r] * sr[r]);
        }
    }

    // ---- PV: O = P @ V ; A = P rows (K=96), B = sVt ----
    bf16x8 ap0, ap1, ap2;
    {
        const int row = 16*w + lr;
        ap0 = *(const bf16x8*)(sP + row*128 + ((8*lg)      ^ (8*(row&7))));
        ap1 = *(const bf16x8*)(sP + row*128 + ((32 + 8*lg) ^ (8*(row&7))));
        ap2 = *(const bf16x8*)(sP + row*128 + ((64 + 8*lg) ^ (8*(row&7))));
    }
    #pragma unroll
    for (int nt = 0; nt < 4; ++nt) {
        const int d = 16*nt + lr;
        bf16x8 b0 = *(const bf16x8*)(sVt + d*128 + ((8*lg)      ^ (8*(d&7))));
        bf16x8 b1 = *(const bf16x8*)(sVt + d*128 + ((32 + 8*lg) ^ (8*(d&7))));
        bf16x8 b2 = *(const bf16x8*)(sVt + d*128 + ((64 + 8*lg) ^ (8*(d&7))));
        f32x4 a = {0.f,0.f,0.f,0.f};
        a = __builtin_amdgcn_mfma_f32_16x16x32_bf16(ap0, b0, a, 0, 0, 0);
        a = __builtin_amdgcn_mfma_f32_16x16x32_bf16(ap1, b1, a, 0, 0, 0);
        a = __builtin_amdgcn_mfma_f32_16x16x32_bf16(ap2, b2, a, 0, 0, 0);
        #pragma unroll
        for (int r = 0; r < 4; ++r) {
            const int i = i0 + r;
            if (i < SEQ) out[base + i*DIM + 16*nt + lr] = a[r];
        }
    }
}

extern "C" void kernel_launch(void* const* d_in, const int* in_sizes, int n_in,
                              void* d_out, int out_size, void* d_ws, size_t ws_size,
                              hipStream_t stream) {
    const float* Q   = (const float*)d_in[0];
    const float* K   = (const float*)d_in[1];
    const float* V   = (const float*)d_in[2];
    const float* emb = (const float*)d_in[3];
    const int*   uc  = (const int*)d_in[4];
    float* out = (float*)d_out;

    const int nbh   = in_sizes[0] / (SEQ * DIM);   // 4096
    const int n_emb = in_sizes[3];                 // 163*64

    short* embw = (short*)d_ws;
    emb_cvt_kernel<<<(n_emb + 255) / 256, 256, 0, stream>>>(emb, embw, n_emb);

    const size_t smem = (size_t)(SP*DIM*2 + DIM*128) * sizeof(short);   // 40960 B
    hipFuncSetAttribute(reinterpret_cast<const void*>(rpsa_kernel),
                        hipFuncAttributeMaxDynamicSharedMemorySize, (int)smem);
    rpsa_kernel<<<nbh, NT, smem, stream>>>(Q, K, V, embw, uc, out);
}

// Round 4
// 86.815 us; speedup vs baseline: 6.0956x; 1.0706x over previous
//
#include <hip/hip_runtime.h>

#define SEQ 81
#define SP  96           // padded rows (6 x 16)
#define DIM 64
#define NT  384          // 6 waves
#define NW  6
#define LDK 68           // sK row stride in shorts (136 B -> bank-spread, 8B-aligned)
#define LDV 100          // sVt row stride in shorts (200 B)
#define LDP 100          // sP row stride in shorts

typedef short bf16x8 __attribute__((ext_vector_type(8)));
typedef short bf16x4 __attribute__((ext_vector_type(4)));
typedef float f32x4  __attribute__((ext_vector_type(4)));

static constexpr float kScale = 0.03608439182435161f;  // 1/sqrt(768)

__device__ __forceinline__ short f2bf(float f) {
    unsigned u = __builtin_bit_cast(unsigned, f);
    u = (u + 0x7FFFu + ((u >> 16) & 1u)) >> 16;   // RNE; inputs finite
    return (short)u;
}
__device__ __forceinline__ float bf2f(short h) {
    unsigned u = ((unsigned)(unsigned short)h) << 16;
    return __builtin_bit_cast(float, u);
}
__device__ __forceinline__ bf16x8 cat8(bf16x4 a, bf16x4 b) {
    bf16x8 r;
    r[0]=a[0]; r[1]=a[1]; r[2]=a[2]; r[3]=a[3];
    r[4]=b[0]; r[5]=b[1]; r[6]=b[2]; r[7]=b[3];
    return r;
}

__global__ void emb_cvt_kernel(const float* __restrict__ in, short* __restrict__ out, int n) {
    int i = blockIdx.x * 256 + threadIdx.x;
    if (i < n) out[i] = f2bf(in[i]);
}

__global__ __launch_bounds__(NT, 8)
void rpsa_kernel(const float* __restrict__ Q, const float* __restrict__ K,
                 const float* __restrict__ V, const short* __restrict__ embw,
                 const int* __restrict__ ucp, float* __restrict__ out)
{
    extern __shared__ char smraw[];
    short* sVt = (short*)smraw;              // [64][100]  12800 B (V^T, bf16)
    short* sK  = (short*)(smraw + 12800);    // [96][68]   13056 B (bf16)
    short* sP  = (short*)(smraw + 12800);    // [96][100]  19200 B bias/P, overlays sK
    // total 32000 B -> 5 blocks/CU

    const int tid = threadIdx.x;
    const size_t base = (size_t)blockIdx.x * (SEQ * DIM);
    const int uc = ucp[0];
    const int w  = tid >> 6, L = tid & 63;
    const int lr = L & 15,  lg = L >> 4;
    const int i0 = 16*w + 4*lg;              // lane's 4 output rows

    // ---- Q A-fragments straight from global, pre-scaled by 1/sqrt(768) ----
    bf16x8 aq0, aq1;
    {
        const int qrow = (16*w + lr < SEQ) ? (16*w + lr) : (SEQ - 1);  // clamp pad lanes
        const float* qp = Q + base + qrow*DIM + 8*lg;
        const f32x4 q0 = *(const f32x4*)(qp);
        const f32x4 q1 = *(const f32x4*)(qp + 4);
        const f32x4 q2 = *(const f32x4*)(qp + 32);
        const f32x4 q3 = *(const f32x4*)(qp + 36);
        #pragma unroll
        for (int t = 0; t < 4; ++t) {
            aq0[t]   = f2bf(q0[t]*kScale);
            aq0[4+t] = f2bf(q1[t]*kScale);
            aq1[t]   = f2bf(q2[t]*kScale);
            aq1[4+t] = f2bf(q3[t]*kScale);
        }
    }

    // ---- stage K bf16 (rows >= 81 zeroed) ----
    for (int u = tid; u < SP * DIM / 8; u += NT) {        // 2 iters
        const int row = u >> 3, so = (u & 7) * 8;
        bf16x4 lo = {0,0,0,0}, hi = {0,0,0,0};
        if (row < SEQ) {
            const f32x4 k0 = *(const f32x4*)(K + base + row*DIM + so);
            const f32x4 k1 = *(const f32x4*)(K + base + row*DIM + so + 4);
            #pragma unroll
            for (int t = 0; t < 4; ++t) { lo[t] = f2bf(k0[t]); hi[t] = f2bf(k1[t]); }
        }
        *(bf16x4*)(sK + row*LDK + so)     = lo;
        *(bf16x4*)(sK + row*LDK + so + 4) = hi;
    }
    // ---- stage V transposed (4x4 register transpose; pad cols j>=81 zeroed) ----
    {
        const int j4 = tid >> 4;          // 0..23
        const int d4 = tid & 15;          // 0..15
        f32x4 rw[4];
        #pragma unroll
        for (int e = 0; e < 4; ++e) {
            const int j = 4*j4 + e;
            rw[e] = (j < SEQ) ? *(const f32x4*)(V + base + j*DIM + 4*d4)
                              : (f32x4){0.f,0.f,0.f,0.f};
        }
        #pragma unroll
        for (int c = 0; c < 4; ++c) {
            const int d = 4*d4 + c;
            bf16x4 pv = { f2bf(rw[0][c]), f2bf(rw[1][c]), f2bf(rw[2][c]), f2bf(rw[3][c]) };
            *(bf16x4*)(sVt + d*LDV + 4*j4) = pv;
        }
    }
    __syncthreads();   // bar1

    // ---- QK^T into register accumulators; causal skips tiles nt > w ----
    f32x4 accs[NW] = {};
    const int ntEnd = uc ? w : (NW - 1);
    #pragma unroll
    for (int nt = 0; nt < NW; ++nt) {
        if (nt > ntEnd) continue;
        const int kr = 16*nt + lr;
        bf16x8 b0 = cat8(*(const bf16x4*)(sK + kr*LDK + 8*lg),
                         *(const bf16x4*)(sK + kr*LDK + 8*lg + 4));
        bf16x8 b1 = cat8(*(const bf16x4*)(sK + kr*LDK + 32 + 8*lg),
                         *(const bf16x4*)(sK + kr*LDK + 32 + 8*lg + 4));
        f32x4 a = accs[nt];
        a = __builtin_amdgcn_mfma_f32_16x16x32_bf16(aq0, b0, a, 0, 0, 0);
        a = __builtin_amdgcn_mfma_f32_16x16x32_bf16(aq1, b1, a, 0, 0, 0);
        accs[nt] = a;
    }
    __syncthreads();   // bar2: sK dead -> sP overlay live

    // ---- Qe bias scatter into sP (bf16; scale already folded into aq) ----
    // pass 1: rel = 80 + (i-j), j <= i  (always)
    #pragma unroll
    for (int nt = 0; nt < NW; ++nt) {
        if (nt > w) continue;
        int erow = (SEQ - 1) + 16*nt + lr;
        if (erow > 2*SEQ) erow = 2*SEQ;          // clamp pad lanes (land in pad rows only)
        bf16x8 b0 = *(const bf16x8*)(embw + erow*DIM + 8*lg);
        bf16x8 b1 = *(const bf16x8*)(embw + erow*DIM + 32 + 8*lg);
        f32x4 a = {0.f,0.f,0.f,0.f};
        a = __builtin_amdgcn_mfma_f32_16x16x32_bf16(aq0, b0, a, 0, 0, 0);
        a = __builtin_amdgcn_mfma_f32_16x16x32_bf16(aq1, b1, a, 0, 0, 0);
        #pragma unroll
        for (int r = 0; r < 4; ++r) {
            const int i = i0 + r;
            const int j = i - (16*nt + lr);
            if (j >= 0) sP[i*LDP + j] = f2bf(a[r]);
        }
    }
    // pass 0: rel = rp in [0,79], j = 80+i-rp > i  (non-causal only)
    if (!uc) {
        #pragma unroll
        for (int nt = 0; nt < NW; ++nt) {
            if (nt < w) continue;
            const int erow = 16*nt + lr;         // <= 95 < 163
            bf16x8 b0 = *(const bf16x8*)(embw + erow*DIM + 8*lg);
            bf16x8 b1 = *(const bf16x8*)(embw + erow*DIM + 32 + 8*lg);
            f32x4 a = {0.f,0.f,0.f,0.f};
            a = __builtin_amdgcn_mfma_f32_16x16x32_bf16(aq0, b0, a, 0, 0, 0);
            a = __builtin_amdgcn_mfma_f32_16x16x32_bf16(aq1, b1, a, 0, 0, 0);
            #pragma unroll
            for (int r = 0; r < 4; ++r) {
                const int i  = i0 + r;
                const int rp = 16*nt + lr;
                if (rp >= i && rp < SEQ - 1)
                    sP[i*LDP + (SEQ - 1 + i - rp)] = f2bf(a[r]);
            }
        }
    }
    // No barrier: each wave's bias slots are produced and consumed by the same wave.

    // ---- in-register softmax; accs reused as x ----
    float mr[4] = {-1e30f, -1e30f, -1e30f, -1e30f};
    #pragma unroll
    for (int nt = 0; nt < NW; ++nt) {
        const bool live = (!uc) || (nt <= w);    // uniform
        const int j = 16*nt + lr;
        #pragma unroll
        for (int r = 0; r < 4; ++r) {
            const int i = i0 + r;
            float v = accs[nt][r];
            if (live) v += bf2f(sP[i*LDP + j]);
            accs[nt][r] = v;
            const int jl = uc ? ((i < SEQ-1) ? i : SEQ-1) : (SEQ-1);
            if (j <= jl) mr[r] = fmaxf(mr[r], v);
        }
    }
    #pragma unroll
    for (int r = 0; r < 4; ++r) {
        float m = mr[r];
        m = fmaxf(m, __shfl_xor(m, 1, 16));
        m = fmaxf(m, __shfl_xor(m, 2, 16));
        m = fmaxf(m, __shfl_xor(m, 4, 16));
        m = fmaxf(m, __shfl_xor(m, 8, 16));
        mr[r] = m;
    }
    float sr[4] = {0.f, 0.f, 0.f, 0.f};
    #pragma unroll
    for (int nt = 0; nt < NW; ++nt) {
        const int j = 16*nt + lr;
        #pragma unroll
        for (int r = 0; r < 4; ++r) {
            const int i = i0 + r;
            const int jl = uc ? ((i < SEQ-1) ? i : SEQ-1) : (SEQ-1);
            const float e = (j <= jl) ? __expf(accs[nt][r] - mr[r]) : 0.f;
            accs[nt][r] = e; sr[r] += e;
        }
    }
    #pragma unroll
    for (int r = 0; r < 4; ++r) {
        float s = sr[r];
        s += __shfl_xor(s, 1, 16);
        s += __shfl_xor(s, 2, 16);
        s += __shfl_xor(s, 4, 16);
        s += __shfl_xor(s, 8, 16);
        sr[r] = 1.f / s;
    }
    // ---- write P (bf16); every slot (i, j<=95) written (masked -> 0) ----
    #pragma unroll
    for (int nt = 0; nt < NW; ++nt) {
        const int j = 16*nt + lr;
        #pragma unroll
        for (int r = 0; r < 4; ++r) {
            const int i = i0 + r;
            sP[i*LDP + j] = f2bf(accs[nt][r] * sr[r]);
        }
    }

    // ---- PV: O = P @ V ; A = P rows (K=96), B = sVt ----
    bf16x8 ap0, ap1, ap2;
    {
        const int row = 16*w + lr;
        ap0 = cat8(*(const bf16x4*)(sP + row*LDP + 8*lg),
                   *(const bf16x4*)(sP + row*LDP + 8*lg + 4));
        ap1 = cat8(*(const bf16x4*)(sP + row*LDP + 32 + 8*lg),
                   *(const bf16x4*)(sP + row*LDP + 32 + 8*lg + 4));
        ap2 = cat8(*(const bf16x4*)(sP + row*LDP + 64 + 8*lg),
                   *(const bf16x4*)(sP + row*LDP + 64 + 8*lg + 4));
    }
    #pragma unroll
    for (int nt = 0; nt < 4; ++nt) {
        const int d = 16*nt + lr;
        bf16x8 b0 = cat8(*(const bf16x4*)(sVt + d*LDV + 8*lg),
                         *(const bf16x4*)(sVt + d*LDV + 8*lg + 4));
        bf16x8 b1 = cat8(*(const bf16x4*)(sVt + d*LDV + 32 + 8*lg),
                         *(const bf16x4*)(sVt + d*LDV + 32 + 8*lg + 4));
        bf16x8 b2 = cat8(*(const bf16x4*)(sVt + d*LDV + 64 + 8*lg),
                         *(const bf16x4*)(sVt + d*LDV + 64 + 8*lg + 4));
        f32x4 a = {0.f,0.f,0.f,0.f};
        a = __builtin_amdgcn_mfma_f32_16x16x32_bf16(ap0, b0, a, 0, 0, 0);
        a = __builtin_amdgcn_mfma_f32_16x16x32_bf16(ap1, b1, a, 0, 0, 0);
        a = __builtin_amdgcn_mfma_f32_16x16x32_bf16(ap2, b2, a, 0, 0, 0);
        #pragma unroll
        for (int r = 0; r < 4; ++r) {
            const int i = i0 + r;
            if (i < SEQ) out[base + i*DIM + 16*nt + lr] = a[r];
        }
    }
}

extern "C" void kernel_launch(void* const* d_in, const int* in_sizes, int n_in,
                              void* d_out, int out_size, void* d_ws, size_t ws_size,
                              hipStream_t stream) {
    const float* Q   = (const float*)d_in[0];
    const float* K   = (const float*)d_in[1];
    const float* V   = (const float*)d_in[2];
    const float* emb = (const float*)d_in[3];
    const int*   uc  = (const int*)d_in[4];
    float* out = (float*)d_out;

    const int nbh   = in_sizes[0] / (SEQ * DIM);   // 4096
    const int n_emb = in_sizes[3];                 // 163*64

    short* embw = (short*)d_ws;
    emb_cvt_kernel<<<(n_emb + 255) / 256, 256, 0, stream>>>(emb, embw, n_emb);

    const size_t smem = 32000;   // sVt 12800 + max(sK 13056, sP 19200)
    hipFuncSetAttribute(reinterpret_cast<const void*>(rpsa_kernel),
                        hipFuncAttributeMaxDynamicSharedMemorySize, (int)smem);
    rpsa_kernel<<<nbh, NT, smem, stream>>>(Q, K, V, embw, uc, out);
}

// Round 5
// 86.731 us; speedup vs baseline: 6.1015x; 1.0010x over previous
//
#include <hip/hip_runtime.h>
#include <hip/hip_bf16.h>

#define SEQ 81
#define DIM 64
#define NT  384          // 6 waves
#define NW  6
#define LDK 68           // sK row stride in shorts (136 B, 8B-aligned, bank-spread)
#define LDV 100          // sVt row stride in shorts (200 B)
#define LDP 100          // sP row stride in shorts

typedef short bf16x8 __attribute__((ext_vector_type(8)));
typedef short bf16x4 __attribute__((ext_vector_type(4)));
typedef float f32x4  __attribute__((ext_vector_type(4)));

static constexpr float kS2 = 0.0520587716f;   // log2(e) / sqrt(768) — folded scale

__device__ __forceinline__ short f2bf(float f) {
    __hip_bfloat16 h = __float2bfloat16(f);   // compiler emits (packed) v_cvt
    return __builtin_bit_cast(short, h);
}
__device__ __forceinline__ float bf2f(short h) {
    unsigned u = ((unsigned)(unsigned short)h) << 16;
    return __builtin_bit_cast(float, u);
}
__device__ __forceinline__ bf16x8 cat8(bf16x4 a, bf16x4 b) {
    bf16x8 r;
    r[0]=a[0]; r[1]=a[1]; r[2]=a[2]; r[3]=a[3];
    r[4]=b[0]; r[5]=b[1]; r[6]=b[2]; r[7]=b[3];
    return r;
}

__global__ void emb_cvt_kernel(const float* __restrict__ in, short* __restrict__ out, int n) {
    int i = blockIdx.x * 256 + threadIdx.x;
    if (i < n) out[i] = f2bf(in[i]);
}

__global__ __launch_bounds__(NT, 8)
void rpsa_kernel(const float* __restrict__ Q, const float* __restrict__ K,
                 const float* __restrict__ V, const short* __restrict__ embw,
                 const int* __restrict__ ucp, float* __restrict__ out)
{
    extern __shared__ char smraw[];
    short* sVt = (short*)smraw;              // [64][100]  12800 B (V^T, bf16)
    short* sK  = (short*)(smraw + 12800);    // [96][68]   13056 B (bf16)
    short* sP  = (short*)(smraw + 12800);    // [96][100]  19200 B bias/P, overlays sK
    // total 32000 B -> 5 blocks/CU

    const int tid = threadIdx.x;
    const size_t base = (size_t)blockIdx.x * (SEQ * DIM);
    const int uc = ucp[0];
    const int w  = tid >> 6, L = tid & 63;
    const int lr = L & 15,  lg = L >> 4;
    const int i0 = 16*w + 4*lg;              // lane's 4 output rows

    // ---- Q A-fragments straight from global, pre-scaled by log2e/sqrt(768) ----
    bf16x8 aq0, aq1;
    {
        const int qrow = (16*w + lr < SEQ) ? (16*w + lr) : (SEQ - 1);  // clamp pad lanes
        const float* qp = Q + base + qrow*DIM + 8*lg;
        const f32x4 q0 = *(const f32x4*)(qp);
        const f32x4 q1 = *(const f32x4*)(qp + 4);
        const f32x4 q2 = *(const f32x4*)(qp + 32);
        const f32x4 q3 = *(const f32x4*)(qp + 36);
        #pragma unroll
        for (int t = 0; t < 4; ++t) {
            aq0[t]   = f2bf(q0[t]*kS2);
            aq0[4+t] = f2bf(q1[t]*kS2);
            aq1[t]   = f2bf(q2[t]*kS2);
            aq1[4+t] = f2bf(q3[t]*kS2);
        }
    }

    // ---- stage K bf16 (rows >= 81 zeroed) ----
    for (int u = tid; u < 96 * DIM / 8; u += NT) {        // 2 iters
        const int row = u >> 3, so = (u & 7) * 8;
        bf16x4 lo = {0,0,0,0}, hi = {0,0,0,0};
        if (row < SEQ) {
            const f32x4 k0 = *(const f32x4*)(K + base + row*DIM + so);
            const f32x4 k1 = *(const f32x4*)(K + base + row*DIM + so + 4);
            #pragma unroll
            for (int t = 0; t < 4; ++t) { lo[t] = f2bf(k0[t]); hi[t] = f2bf(k1[t]); }
        }
        *(bf16x4*)(sK + row*LDK + so)     = lo;
        *(bf16x4*)(sK + row*LDK + so + 4) = hi;
    }
    // ---- stage V transposed (4x4 register transpose; pad cols j>=81 zeroed) ----
    {
        const int j4 = tid >> 4;          // 0..23
        const int d4 = tid & 15;          // 0..15
        f32x4 rw[4];
        #pragma unroll
        for (int e = 0; e < 4; ++e) {
            const int j = 4*j4 + e;
            rw[e] = (j < SEQ) ? *(const f32x4*)(V + base + j*DIM + 4*d4)
                              : (f32x4){0.f,0.f,0.f,0.f};
        }
        #pragma unroll
        for (int c = 0; c < 4; ++c) {
            const int d = 4*d4 + c;
            bf16x4 pv = { f2bf(rw[0][c]), f2bf(rw[1][c]), f2bf(rw[2][c]), f2bf(rw[3][c]) };
            *(bf16x4*)(sVt + d*LDV + 4*j4) = pv;
        }
    }

    // ---- Qe pass 1 PREFETCH (no LDS needed): rel = 80 + (i-j), j <= i ----
    // Computed before bar1 so the emb L2 loads + MFMAs hide under staging latency.
    // Results packed bf16, scattered into sP only after bar2.
    bf16x4 qe[NW];
    #pragma unroll
    for (int nt = 0; nt < NW; ++nt) {
        if (nt > w) continue;
        int erow = (SEQ - 1) + 16*nt + lr;
        if (erow > 2*SEQ) erow = 2*SEQ;          // clamp pad lanes
        bf16x8 b0 = *(const bf16x8*)(embw + erow*DIM + 8*lg);
        bf16x8 b1 = *(const bf16x8*)(embw + erow*DIM + 32 + 8*lg);
        f32x4 a = {0.f,0.f,0.f,0.f};
        a = __builtin_amdgcn_mfma_f32_16x16x32_bf16(aq0, b0, a, 0, 0, 0);
        a = __builtin_amdgcn_mfma_f32_16x16x32_bf16(aq1, b1, a, 0, 0, 0);
        bf16x4 p = { f2bf(a[0]), f2bf(a[1]), f2bf(a[2]), f2bf(a[3]) };
        qe[nt] = p;
    }
    __syncthreads();   // bar1

    // ---- QK^T into register accumulators; causal skips tiles nt > w ----
    f32x4 accs[NW] = {};
    const int ntEnd = uc ? w : (NW - 1);
    #pragma unroll
    for (int nt = 0; nt < NW; ++nt) {
        if (nt > ntEnd) continue;
        const int kr = 16*nt + lr;
        bf16x8 b0 = cat8(*(const bf16x4*)(sK + kr*LDK + 8*lg),
                         *(const bf16x4*)(sK + kr*LDK + 8*lg + 4));
        bf16x8 b1 = cat8(*(const bf16x4*)(sK + kr*LDK + 32 + 8*lg),
                         *(const bf16x4*)(sK + kr*LDK + 32 + 8*lg + 4));
        f32x4 a = accs[nt];
        a = __builtin_amdgcn_mfma_f32_16x16x32_bf16(aq0, b0, a, 0, 0, 0);
        a = __builtin_amdgcn_mfma_f32_16x16x32_bf16(aq1, b1, a, 0, 0, 0);
        accs[nt] = a;
    }
    __syncthreads();   // bar2: sK dead -> sP overlay live

    // ---- scatter prefetched pass-1 bias into sP ----
    #pragma unroll
    for (int nt = 0; nt < NW; ++nt) {
        if (nt > w) continue;
        #pragma unroll
        for (int r = 0; r < 4; ++r) {
            const int i = i0 + r;
            const int j = i - (16*nt + lr);
            if (j >= 0) sP[i*LDP + j] = qe[nt][r];
        }
    }
    // ---- pass 0: rel = rp in [0,79], j = 80+i-rp > i  (non-causal only) ----
    if (!uc) {
        #pragma unroll
        for (int nt = 0; nt < NW; ++nt) {
            if (nt < w) continue;
            const int erow = 16*nt + lr;         // <= 95 < 163
            bf16x8 b0 = *(const bf16x8*)(embw + erow*DIM + 8*lg);
            bf16x8 b1 = *(const bf16x8*)(embw + erow*DIM + 32 + 8*lg);
            f32x4 a = {0.f,0.f,0.f,0.f};
            a = __builtin_amdgcn_mfma_f32_16x16x32_bf16(aq0, b0, a, 0, 0, 0);
            a = __builtin_amdgcn_mfma_f32_16x16x32_bf16(aq1, b1, a, 0, 0, 0);
            #pragma unroll
            for (int r = 0; r < 4; ++r) {
                const int i  = i0 + r;
                const int rp = 16*nt + lr;
                if (rp >= i && rp < SEQ - 1)
                    sP[i*LDP + (SEQ - 1 + i - rp)] = f2bf(a[r]);
            }
        }
    }
    // No barrier: each wave's bias slots are produced and consumed by the same wave.

    // ---- in-register softmax (base-2; scale pre-folded); accs reused as x ----
    float mr[4] = {-1e30f, -1e30f, -1e30f, -1e30f};
    #pragma unroll
    for (int nt = 0; nt < NW; ++nt) {
        if (uc && nt > w) continue;              // dead tiles stay 0
        const int j = 16*nt + lr;
        #pragma unroll
        for (int r = 0; r < 4; ++r) {
            const int i = i0 + r;
            float v = accs[nt][r] + bf2f(sP[i*LDP + j]);
            accs[nt][r] = v;
            const int jl = uc ? ((i < SEQ-1) ? i : SEQ-1) : (SEQ-1);
            if (j <= jl) mr[r] = fmaxf(mr[r], v);
        }
    }
    #pragma unroll
    for (int r = 0; r < 4; ++r) {
        float m = mr[r];
        m = fmaxf(m, __shfl_xor(m, 1, 16));
        m = fmaxf(m, __shfl_xor(m, 2, 16));
        m = fmaxf(m, __shfl_xor(m, 4, 16));
        m = fmaxf(m, __shfl_xor(m, 8, 16));
        mr[r] = m;
    }
    float sr[4] = {0.f, 0.f, 0.f, 0.f};
    #pragma unroll
    for (int nt = 0; nt < NW; ++nt) {
        if (uc && nt > w) continue;              // accs stays 0 -> P written 0
        const int j = 16*nt + lr;
        #pragma unroll
        for (int r = 0; r < 4; ++r) {
            const int i = i0 + r;
            const int jl = uc ? ((i < SEQ-1) ? i : SEQ-1) : (SEQ-1);
            const float e = (j <= jl) ? exp2f(accs[nt][r] - mr[r]) : 0.f;
            accs[nt][r] = e; sr[r] += e;
        }
    }
    #pragma unroll
    for (int r = 0; r < 4; ++r) {
        float s = sr[r];
        s += __shfl_xor(s, 1, 16);
        s += __shfl_xor(s, 2, 16);
        s += __shfl_xor(s, 4, 16);
        s += __shfl_xor(s, 8, 16);
        sr[r] = 1.f / s;
    }
    // ---- write P (bf16); every slot (i, j<=95) written (masked -> 0) ----
    #pragma unroll
    for (int nt = 0; nt < NW; ++nt) {
        const int j = 16*nt + lr;
        #pragma unroll
        for (int r = 0; r < 4; ++r) {
            const int i = i0 + r;
            sP[i*LDP + j] = f2bf(accs[nt][r] * sr[r]);
        }
    }

    // ---- PV: O = P @ V ; A = P rows (K=96), B = sVt ----
    bf16x8 ap0, ap1, ap2;
    {
        const int row = 16*w + lr;
        ap0 = cat8(*(const bf16x4*)(sP + row*LDP + 8*lg),
                   *(const bf16x4*)(sP + row*LDP + 8*lg + 4));
        ap1 = cat8(*(const bf16x4*)(sP + row*LDP + 32 + 8*lg),
                   *(const bf16x4*)(sP + row*LDP + 32 + 8*lg + 4));
        ap2 = cat8(*(const bf16x4*)(sP + row*LDP + 64 + 8*lg),
                   *(const bf16x4*)(sP + row*LDP + 64 + 8*lg + 4));
    }
    #pragma unroll
    for (int nt = 0; nt < 4; ++nt) {
        const int d = 16*nt + lr;
        bf16x8 b0 = cat8(*(const bf16x4*)(sVt + d*LDV + 8*lg),
                         *(const bf16x4*)(sVt + d*LDV + 8*lg + 4));
        bf16x8 b1 = cat8(*(const bf16x4*)(sVt + d*LDV + 32 + 8*lg),
                         *(const bf16x4*)(sVt + d*LDV + 32 + 8*lg + 4));
        bf16x8 b2 = cat8(*(const bf16x4*)(sVt + d*LDV + 64 + 8*lg),
                         *(const bf16x4*)(sVt + d*LDV + 64 + 8*lg + 4));
        f32x4 a = {0.f,0.f,0.f,0.f};
        a = __builtin_amdgcn_mfma_f32_16x16x32_bf16(ap0, b0, a, 0, 0, 0);
        a = __builtin_amdgcn_mfma_f32_16x16x32_bf16(ap1, b1, a, 0, 0, 0);
        a = __builtin_amdgcn_mfma_f32_16x16x32_bf16(ap2, b2, a, 0, 0, 0);
        #pragma unroll
        for (int r = 0; r < 4; ++r) {
            const int i = i0 + r;
            if (i < SEQ) out[base + i*DIM + 16*nt + lr] = a[r];
        }
    }
}

extern "C" void kernel_launch(void* const* d_in, const int* in_sizes, int n_in,
                              void* d_out, int out_size, void* d_ws, size_t ws_size,
                              hipStream_t stream) {
    const float* Q   = (const float*)d_in[0];
    const float* K   = (const float*)d_in[1];
    const float* V   = (const float*)d_in[2];
    const float* emb = (const float*)d_in[3];
    const int*   uc  = (const int*)d_in[4];
    float* out = (float*)d_out;

    const int nbh   = in_sizes[0] / (SEQ * DIM);   // 4096
    const int n_emb = in_sizes[3];                 // 163*64

    short* embw = (short*)d_ws;
    emb_cvt_kernel<<<(n_emb + 255) / 256, 256, 0, stream>>>(emb, embw, n_emb);

    const size_t smem = 32000;   // sVt 12800 + max(sK 13056, sP 19200)
    hipFuncSetAttribute(reinterpret_cast<const void*>(rpsa_kernel),
                        hipFuncAttributeMaxDynamicSharedMemorySize, (int)smem);
    rpsa_kernel<<<nbh, NT, smem, stream>>>(Q, K, V, embw, uc, out);
}

// Round 6
// 83.854 us; speedup vs baseline: 6.3108x; 1.0343x over previous
//
#include <hip/hip_runtime.h>
#include <hip/hip_bf16.h>

#define SEQ 81
#define DIM 64
#define NT  384          // 6 waves
#define NW  6
#define LDK 68           // sK row stride in shorts (136 B)
#define LDV 100          // sVt row stride in shorts (200 B)
#define LDP 100          // sP row stride in shorts (200 B)

typedef short bf16x8 __attribute__((ext_vector_type(8)));
typedef short bf16x4 __attribute__((ext_vector_type(4)));
typedef float f32x4  __attribute__((ext_vector_type(4)));

static constexpr float kS2 = 0.0520587716f;   // log2(e) / sqrt(768) — folded scale

__device__ __forceinline__ short f2bf(float f) {
    __hip_bfloat16 h = __float2bfloat16(f);
    return __builtin_bit_cast(short, h);
}
__device__ __forceinline__ float bf2f(short h) {
    unsigned u = ((unsigned)(unsigned short)h) << 16;
    return __builtin_bit_cast(float, u);
}
__device__ __forceinline__ bf16x8 cat8(bf16x4 a, bf16x4 b) {
    bf16x8 r;
    r[0]=a[0]; r[1]=a[1]; r[2]=a[2]; r[3]=a[3];
    r[4]=b[0]; r[5]=b[1]; r[6]=b[2]; r[7]=b[3];
    return r;
}

__global__ void emb_cvt_kernel(const float* __restrict__ in, short* __restrict__ out, int n) {
    int i = blockIdx.x * 256 + threadIdx.x;
    if (i < n) out[i] = f2bf(in[i]);
}

// Swapped-operand layout: all MFMAs are mfma(A=other, B=Q/P band), so each lane's
// C fragment is (i = 16w + (lane&15), {j or d} = 16nt + 4*(lane>>4) + r), r=0..3.
// => lane owns 4 CONSECUTIVE columns of its own row: b64 LDS ops, float4 out store.
__global__ __launch_bounds__(NT, 8)
void rpsa_kernel(const float* __restrict__ Q, const float* __restrict__ K,
                 const float* __restrict__ V, const short* __restrict__ embw,
                 const int* __restrict__ ucp, float* __restrict__ out)
{
    extern __shared__ char smraw[];
    short* sVt = (short*)smraw;              // [64][100]  12800 B (V^T, bf16)
    short* sK  = (short*)(smraw + 12800);    // [96][68]   13056 B (bf16)
    short* sP  = (short*)(smraw + 12800);    // [96][100]  19200 B bias/P, overlays sK
    // total 32000 B -> 5 blocks/CU

    const int tid = threadIdx.x;
    const size_t base = (size_t)blockIdx.x * (SEQ * DIM);
    const int uc = ucp[0];
    const int w  = tid >> 6, L = tid & 63;
    const int lr = L & 15,  lg = L >> 4;
    const int iRow = 16*w + lr;              // lane's own row (softmax + output)

    // ---- Q B-fragment straight from global, pre-scaled by log2e/sqrt(768) ----
    bf16x8 aq0, aq1;
    {
        const int qrow = (iRow < SEQ) ? iRow : (SEQ - 1);   // clamp pad lanes
        const float* qp = Q + base + qrow*DIM + 8*lg;
        const f32x4 q0 = *(const f32x4*)(qp);
        const f32x4 q1 = *(const f32x4*)(qp + 4);
        const f32x4 q2 = *(const f32x4*)(qp + 32);
        const f32x4 q3 = *(const f32x4*)(qp + 36);
        #pragma unroll
        for (int t = 0; t < 4; ++t) {
            aq0[t]   = f2bf(q0[t]*kS2);
            aq0[4+t] = f2bf(q1[t]*kS2);
            aq1[t]   = f2bf(q2[t]*kS2);
            aq1[4+t] = f2bf(q3[t]*kS2);
        }
    }

    // ---- stage K bf16 (rows >= 81 zeroed) ----
    for (int u = tid; u < 96 * DIM / 8; u += NT) {        // 2 iters
        const int row = u >> 3, so = (u & 7) * 8;
        bf16x4 lo = {0,0,0,0}, hi = {0,0,0,0};
        if (row < SEQ) {
            const f32x4 k0 = *(const f32x4*)(K + base + row*DIM + so);
            const f32x4 k1 = *(const f32x4*)(K + base + row*DIM + so + 4);
            #pragma unroll
            for (int t = 0; t < 4; ++t) { lo[t] = f2bf(k0[t]); hi[t] = f2bf(k1[t]); }
        }
        *(bf16x4*)(sK + row*LDK + so)     = lo;
        *(bf16x4*)(sK + row*LDK + so + 4) = hi;
    }
    // ---- stage V transposed (4x4 register transpose; pad cols j>=81 zeroed) ----
    {
        const int j4 = tid >> 4;          // 0..23
        const int d4 = tid & 15;          // 0..15
        f32x4 rw[4];
        #pragma unroll
        for (int e = 0; e < 4; ++e) {
            const int j = 4*j4 + e;
            rw[e] = (j < SEQ) ? *(const f32x4*)(V + base + j*DIM + 4*d4)
                              : (f32x4){0.f,0.f,0.f,0.f};
        }
        #pragma unroll
        for (int c = 0; c < 4; ++c) {
            const int d = 4*d4 + c;
            bf16x4 pv = { f2bf(rw[0][c]), f2bf(rw[1][c]), f2bf(rw[2][c]), f2bf(rw[3][c]) };
            *(bf16x4*)(sVt + d*LDV + 4*j4) = pv;
        }
    }

    // ---- Qe pass-1 prefetch (swapped; no LDS): lane gets Qe[iRow][rel=80+16nt2+4lg+r]
    bf16x4 qe[NW];
    #pragma unroll
    for (int nt2 = 0; nt2 < NW; ++nt2) {
        if (nt2 > w) continue;
        int erow = 80 + 16*nt2 + lr;
        if (erow > 2*SEQ) erow = 2*SEQ;          // clamp; corrupted rel>162 -> j<0 or pad rows
        bf16x8 e0 = *(const bf16x8*)(embw + erow*DIM + 8*lg);
        bf16x8 e1 = *(const bf16x8*)(embw + erow*DIM + 32 + 8*lg);
        f32x4 a = {0.f,0.f,0.f,0.f};
        a = __builtin_amdgcn_mfma_f32_16x16x32_bf16(e0, aq0, a, 0, 0, 0);
        a = __builtin_amdgcn_mfma_f32_16x16x32_bf16(e1, aq1, a, 0, 0, 0);
        bf16x4 p = { f2bf(a[0]), f2bf(a[1]), f2bf(a[2]), f2bf(a[3]) };
        qe[nt2] = p;
    }
    __syncthreads();   // bar1

    // ---- QK^T (swapped): accs[nt][r] = S[iRow][j = 16nt + 4lg + r] ----
    f32x4 accs[NW] = {};
    const int ntEnd = uc ? w : (NW - 1);
    #pragma unroll
    for (int nt = 0; nt < NW; ++nt) {
        if (nt > ntEnd) continue;
        const int kr = 16*nt + lr;
        bf16x8 b0 = cat8(*(const bf16x4*)(sK + kr*LDK + 8*lg),
                         *(const bf16x4*)(sK + kr*LDK + 8*lg + 4));
        bf16x8 b1 = cat8(*(const bf16x4*)(sK + kr*LDK + 32 + 8*lg),
                         *(const bf16x4*)(sK + kr*LDK + 32 + 8*lg + 4));
        f32x4 a = accs[nt];
        a = __builtin_amdgcn_mfma_f32_16x16x32_bf16(b0, aq0, a, 0, 0, 0);
        a = __builtin_amdgcn_mfma_f32_16x16x32_bf16(b1, aq1, a, 0, 0, 0);
        accs[nt] = a;
    }
    __syncthreads();   // bar2: sK dead -> sP overlay live

    // ---- scatter pass-1 bias into sP (rows = own band -> race-free) ----
    #pragma unroll
    for (int nt2 = 0; nt2 < NW; ++nt2) {
        if (nt2 > w) continue;
        #pragma unroll
        for (int r = 0; r < 4; ++r) {
            const int j = 16*(w - nt2) + lr - 4*lg - r;   // j = iRow - (rel-80)
            if (j >= 0) sP[iRow*LDP + j] = qe[nt2][r];
        }
    }
    // ---- pass-0 (non-causal only): rel in [i,79], j = 80+i-rel > i ----
    if (!uc) {
        #pragma unroll
        for (int nt2 = 0; nt2 < NW - 1; ++nt2) {
            if (nt2 < w) continue;
            const int erow = 16*nt2 + lr;        // <= 79
            bf16x8 e0 = *(const bf16x8*)(embw + erow*DIM + 8*lg);
            bf16x8 e1 = *(const bf16x8*)(embw + erow*DIM + 32 + 8*lg);
            f32x4 a = {0.f,0.f,0.f,0.f};
            a = __builtin_amdgcn_mfma_f32_16x16x32_bf16(e0, aq0, a, 0, 0, 0);
            a = __builtin_amdgcn_mfma_f32_16x16x32_bf16(e1, aq1, a, 0, 0, 0);
            #pragma unroll
            for (int r = 0; r < 4; ++r) {
                const int rel = 16*nt2 + 4*lg + r;
                if (rel >= iRow) sP[iRow*LDP + (80 + iRow - rel)] = f2bf(a[r]);
            }
        }
    }
    // No barrier: each wave's bias slots are produced and consumed by the same wave.

    // ---- fused softmax, no max-subtraction (scores bounded; shift-invariant) ----
    const int jmax = uc ? ((iRow < SEQ-1) ? iRow : SEQ-1) : (SEQ-1);
    float sum = 0.f;
    #pragma unroll
    for (int nt = 0; nt < NW; ++nt) {
        short* slot = sP + iRow*LDP + 16*nt + 4*lg;
        if (nt <= ntEnd) {
            bf16x4 bias = *(const bf16x4*)(slot);
            bf16x4 p;
            #pragma unroll
            for (int r = 0; r < 4; ++r) {
                const int j = 16*nt + 4*lg + r;
                const float x = accs[nt][r] + bf2f(bias[r]);
                const float e = (j <= jmax) ? exp2f(x) : 0.f;
                sum += e;
                p[r] = f2bf(e);
            }
            *(bf16x4*)(slot) = p;
        } else {
            *(bf16x4*)(slot) = (bf16x4){0,0,0,0};   // dead causal tiles -> P = 0
        }
    }
    sum += __shfl_xor(sum, 16);
    sum += __shfl_xor(sum, 32);
    const float inv = 1.f / sum;

    // ---- PV (swapped): A = Vt tiles, B = P rows; lane gets O[iRow][d=16nt+4lg+r] ----
    bf16x8 ap0, ap1, ap2;
    {
        ap0 = cat8(*(const bf16x4*)(sP + iRow*LDP + 8*lg),
                   *(const bf16x4*)(sP + iRow*LDP + 8*lg + 4));
        ap1 = cat8(*(const bf16x4*)(sP + iRow*LDP + 32 + 8*lg),
                   *(const bf16x4*)(sP + iRow*LDP + 32 + 8*lg + 4));
        ap2 = cat8(*(const bf16x4*)(sP + iRow*LDP + 64 + 8*lg),
                   *(const bf16x4*)(sP + iRow*LDP + 64 + 8*lg + 4));
    }
    #pragma unroll
    for (int nt = 0; nt < 4; ++nt) {
        const int d = 16*nt + lr;
        bf16x8 b0 = cat8(*(const bf16x4*)(sVt + d*LDV + 8*lg),
                         *(const bf16x4*)(sVt + d*LDV + 8*lg + 4));
        bf16x8 b1 = cat8(*(const bf16x4*)(sVt + d*LDV + 32 + 8*lg),
                         *(const bf16x4*)(sVt + d*LDV + 32 + 8*lg + 4));
        bf16x8 b2 = cat8(*(const bf16x4*)(sVt + d*LDV + 64 + 8*lg),
                         *(const bf16x4*)(sVt + d*LDV + 64 + 8*lg + 4));
        f32x4 a = {0.f,0.f,0.f,0.f};
        a = __builtin_amdgcn_mfma_f32_16x16x32_bf16(b0, ap0, a, 0, 0, 0);
        a = __builtin_amdgcn_mfma_f32_16x16x32_bf16(b1, ap1, a, 0, 0, 0);
        a = __builtin_amdgcn_mfma_f32_16x16x32_bf16(b2, ap2, a, 0, 0, 0);
        if (iRow < SEQ) {
            f32x4 o = { a[0]*inv, a[1]*inv, a[2]*inv, a[3]*inv };
            *(f32x4*)(out + base + iRow*DIM + 16*nt + 4*lg) = o;
        }
    }
}

extern "C" void kernel_launch(void* const* d_in, const int* in_sizes, int n_in,
                              void* d_out, int out_size, void* d_ws, size_t ws_size,
                              hipStream_t stream) {
    const float* Q   = (const float*)d_in[0];
    const float* K   = (const float*)d_in[1];
    const float* V   = (const float*)d_in[2];
    const float* emb = (const float*)d_in[3];
    const int*   uc  = (const int*)d_in[4];
    float* out = (float*)d_out;

    const int nbh   = in_sizes[0] / (SEQ * DIM);   // 4096
    const int n_emb = in_sizes[3];                 // 163*64

    short* embw = (short*)d_ws;
    emb_cvt_kernel<<<(n_emb + 255) / 256, 256, 0, stream>>>(emb, embw, n_emb);

    const size_t smem = 32000;   // sVt 12800 + max(sK 13056, sP 19200)
    hipFuncSetAttribute(reinterpret_cast<const void*>(rpsa_kernel),
                        hipFuncAttributeMaxDynamicSharedMemorySize, (int)smem);
    rpsa_kernel<<<nbh, NT, smem, stream>>>(Q, K, V, embw, uc, out);
}